// Round 19
// baseline (538.465 us; speedup 1.0000x reference)
//
#include <hip/hip_runtime.h>
#include <hip/hip_bf16.h>

// TransformerLayer on MI355X (gfx950). Round 19:
//  - attn = R15's proven-correct structure (pass A rowsum TK=32 + pass B,
//    unified K staging, 37.6KB LDS) with __launch_bounds__(256,3):
//    R15's (256,4) forced VGPR<=64 -> spill catastrophe; (256,3) caps ~170,
//    kernel needs ~125 -> no spill, 3-4 blocks/CU (12-16 waves) TLP test.
//  - GEMM stack (256,2) as R17 (proven). R18's one-pass+pnorm reverted
//    (3x P traffic > saved QK compute).

typedef __bf16 bf16_t;
typedef __bf16 bf16x8 __attribute__((ext_vector_type(8)));
typedef __bf16 bf16x4 __attribute__((ext_vector_type(4)));
typedef float  f32x4  __attribute__((ext_vector_type(4)));

#define DEV __device__ __forceinline__

DEV f32x4 mfma16(bf16x8 a, bf16x8 b, f32x4 c) {
  return __builtin_amdgcn_mfma_f32_16x16x32_bf16(a, b, c, 0, 0, 0);
}

DEV void gload16(const void* g, void* l) {
  __builtin_amdgcn_global_load_lds(
      (const __attribute__((address_space(1))) unsigned int*)g,
      (__attribute__((address_space(3))) unsigned int*)l, 16, 0, 0);
}

// ---------------- fused LN1 + weight cvt (grid 1024 + 2560) ----------------
__global__ __launch_bounds__(256) void k1_lncvt(
    const float* __restrict__ x, const float* __restrict__ g, const float* __restrict__ bta,
    float* __restrict__ of, bf16_t* __restrict__ ob,
    const float* __restrict__ s0, const float* __restrict__ s1,
    const float* __restrict__ s2, const float* __restrict__ s3,
    const float* __restrict__ s4, const float* __restrict__ s5,
    bf16_t* __restrict__ d0, bf16_t* __restrict__ d1, bf16_t* __restrict__ d2,
    bf16_t* __restrict__ d3, bf16_t* __restrict__ d4, bf16_t* __restrict__ d5) {
  int bid = blockIdx.x;
  if (bid < 1024) {
    int row = bid * 4 + (threadIdx.x >> 6);
    int l = threadIdx.x & 63;
    const float4 v = *(const float4*)(x + (size_t)row * 256 + l * 4);
    float s  = v.x + v.y + v.z + v.w;
    float s2 = v.x*v.x + v.y*v.y + v.z*v.z + v.w*v.w;
#pragma unroll
    for (int o = 1; o < 64; o <<= 1) { s += __shfl_xor(s, o, 64); s2 += __shfl_xor(s2, o, 64); }
    float m   = s * (1.f/256.f);
    float var = s2 * (1.f/256.f) - m * m;
    float rs  = rsqrtf(var + 1e-9f);
    const float4 gv = *(const float4*)(g   + l * 4);
    const float4 bv = *(const float4*)(bta + l * 4);
    float4 y;
    y.x = (v.x - m) * rs * gv.x + bv.x;
    y.y = (v.y - m) * rs * gv.y + bv.y;
    y.z = (v.z - m) * rs * gv.z + bv.z;
    y.w = (v.w - m) * rs * gv.w + bv.w;
    *(float4*)(of + (size_t)row * 256 + l * 4) = y;
    bf16x4 yb = { (bf16_t)y.x, (bf16_t)y.y, (bf16_t)y.z, (bf16_t)y.w };
    *(bf16x4*)(ob + (size_t)row * 256 + l * 4) = yb;
  } else {
    int i = (bid - 1024) * 256 + threadIdx.x;
    const float* s; bf16_t* d; int off;
    if      (i < 131072) { s = s0; d = d0; off = i; }
    else if (i < 262144) { s = s1; d = d1; off = i - 131072; }
    else if (i < 393216) { s = s2; d = d2; off = i - 262144; }
    else if (i < 524288) { s = s3; d = d3; off = i - 393216; }
    else if (i < 589824) { s = s4; d = d4; off = i - 524288; }
    else                 { s = s5; d = d5; off = i - 589824; }
    float4 v = ((const float4*)s)[off];
    bf16x4 o = { (bf16_t)v.x, (bf16_t)v.y, (bf16_t)v.z, (bf16_t)v.w };
    ((bf16x4*)d)[off] = o;
  }
}

// ---------------- 2-phase double-buffered 128x128 GEMM core ----------------
DEV void gemm_core(const bf16_t* __restrict__ A, const bf16_t* __restrict__ W,
                   int lda, int row0, int col0, int k0, int kiters,
                   char* Asb, char* Bsb, f32x4 (&acc)[4][4]) {
  int tid = threadIdx.x, w = tid >> 6, l = tid & 63, l15 = l & 15, lhi = l >> 4;
  int wr = (w >> 1) * 64, wc = (w & 1) * 64;

#define STAGE(buf, kk) do {                                                   \
    char* Ad = Asb + (buf) * 8192 + w * 1024;                                 \
    char* Bd = Bsb + (buf) * 8192 + w * 1024;                                 \
    _Pragma("unroll")                                                         \
    for (int j = 0; j < 2; ++j) {                                             \
      int idx = (j * 256 + tid) * 8; int r = idx >> 5, c = idx & 31;          \
      gload16(A + (size_t)(row0 + r) * lda + (kk) + c, Ad + j * 4096);        \
      gload16(W + (size_t)(col0 + r) * lda + (kk) + c, Bd + j * 4096);        \
    } } while (0)

  STAGE(0, k0);
  for (int t = 0; t < kiters; ++t) {
    int cur = t & 1;
    if (t + 1 < kiters) {
      STAGE(cur ^ 1, k0 + (t + 1) * 32);
      asm volatile("s_waitcnt vmcnt(4)" ::: "memory");
    } else {
      asm volatile("s_waitcnt vmcnt(0)" ::: "memory");
    }
    __builtin_amdgcn_s_barrier();
    asm volatile("" ::: "memory");
    const bf16_t* As = (const bf16_t*)(Asb + cur * 8192);
    const bf16_t* Bs = (const bf16_t*)(Bsb + cur * 8192);
    bf16x8 af[4], bfr[4];
#pragma unroll
    for (int m = 0; m < 4; ++m)
      af[m] = *(const bf16x8*)(As + (wr + 16 * m + l15) * 32 + lhi * 8);
#pragma unroll
    for (int n = 0; n < 4; ++n)
      bfr[n] = *(const bf16x8*)(Bs + (wc + 16 * n + l15) * 32 + lhi * 8);
#pragma unroll
    for (int m = 0; m < 4; ++m)
#pragma unroll
      for (int n = 0; n < 4; ++n)
        acc[m][n] = mfma16(af[m], bfr[n], acc[m][n]);
    asm volatile("s_waitcnt lgkmcnt(0)" ::: "memory");
    __builtin_amdgcn_s_barrier();
  }
#undef STAGE
}

// ---------------- fused QKV: grid (48, 32); V written TILED ----------------
// vt layout: [bh][kt=s/32][256 d][32 s] bf16 (16KB per tile)
__global__ __launch_bounds__(256, 2) void gemm_qkv(
    const bf16_t* __restrict__ A,
    const bf16_t* __restrict__ W0, const bf16_t* __restrict__ W1, const bf16_t* __restrict__ W2,
    const float* __restrict__ b0, const float* __restrict__ b1, const float* __restrict__ b2,
    bf16_t* __restrict__ qo, bf16_t* __restrict__ ko, bf16_t* __restrict__ vto) {
  __shared__ char smem[34816];   // staging 32KB | V-transpose 128x136 bf16
  char* Asb = smem;
  char* Bsb = smem + 16384;
  int bx = blockIdx.x;
  int wsel = bx >> 4, cb = bx & 15;
  const bf16_t* W    = wsel == 0 ? W0 : (wsel == 1 ? W1 : W2);
  const float*  bias = wsel == 0 ? b0 : (wsel == 1 ? b1 : b2);
  int row0 = blockIdx.y * 128, col0 = cb * 128;
  f32x4 acc[4][4] = {};
  gemm_core(A, W, 256, row0, col0, 0, 8, Asb, Bsb, acc);

  int tid = threadIdx.x, w = tid >> 6, l = tid & 63, l15 = l & 15, lhi = l >> 4;
  int wr = (w >> 1) * 64, wc = (w & 1) * 64;

  if (wsel < 2) {
    bf16_t* out = wsel == 0 ? qo : ko;
#pragma unroll
    for (int m = 0; m < 4; ++m)
#pragma unroll
      for (int n = 0; n < 4; ++n)
#pragma unroll
        for (int j = 0; j < 4; ++j) {
          int row = row0 + wr + 16 * m + lhi * 4 + j;
          int col = col0 + wc + 16 * n + l15;
          float v = acc[m][n][j] + bias[col];
          out[((size_t)((row >> 11) * 8 + (col >> 8)) * 2048 + (row & 2047)) * 256 + (col & 255)] = (bf16_t)v;
        }
  } else {
    // V: transpose in LDS, write TILED V^T: vt[bh][kt][d][32]
    __syncthreads();   // full drain before overwriting staging LDS
    bf16_t* T = (bf16_t*)smem;   // [128 d][136 stride] bf16
#pragma unroll
    for (int m = 0; m < 4; ++m)
#pragma unroll
      for (int n = 0; n < 4; ++n) {
        int d = wc + 16 * n + l15;
        int s = wr + 16 * m + lhi * 4;
        bf16x4 v4;
#pragma unroll
        for (int j = 0; j < 4; ++j) v4[j] = (bf16_t)(acc[m][n][j] + bias[col0 + d]);
        *(bf16x4*)(T + d * 136 + s) = v4;
      }
    __syncthreads();
    int bh = ((row0 >> 11) << 3) + (col0 >> 8);
    int d0 = col0 & 255, s0g = row0 & 2047;
#pragma unroll
    for (int p = 0; p < 8; ++p) {
      int idx = p * 256 + tid;
      int d = idx >> 4, c = (idx & 15) * 8;
      bf16x8 v8 = *(const bf16x8*)(T + d * 136 + c);
      int kt = (s0g + c) >> 5, so = c & 31;
      *(bf16x8*)(vto + (((size_t)bh * 64 + kt) * 256 + d0 + d) * 32 + so) = v8;
    }
  }
}

// ---------------- split-K partial GEMM: N=256, grid (2, 32, 4) ----------------
__global__ __launch_bounds__(256, 2) void gemm_part(
    const bf16_t* __restrict__ A, const bf16_t* __restrict__ W,
    int lda, int ksub, float* __restrict__ parts) {
  __shared__ char Asb[2 * 8192];
  __shared__ char Bsb[2 * 8192];
  int z = blockIdx.z;
  int row0 = blockIdx.y * 128, col0 = blockIdx.x * 128;
  f32x4 acc[4][4] = {};
  gemm_core(A, W, lda, row0, col0, z * ksub, ksub >> 5, Asb, Bsb, acc);

  int tid = threadIdx.x, w = tid >> 6, l = tid & 63, l15 = l & 15, lhi = l >> 4;
  int wr = (w >> 1) * 64, wc = (w & 1) * 64;
  float* p = parts + (size_t)z * 1048576;
#pragma unroll
  for (int m = 0; m < 4; ++m)
#pragma unroll
    for (int n = 0; n < 4; ++n)
#pragma unroll
      for (int j = 0; j < 4; ++j) {
        int row = row0 + wr + 16 * m + lhi * 4 + j;
        int col = col0 + wc + 16 * n + l15;
        p[(size_t)row * 256 + col] = acc[m][n][j];
      }
}

// ---------------- reduce 4 partials + bias + residual (final out) ----------------
__global__ __launch_bounds__(256) void reduce4(
    const float* __restrict__ parts, const float* __restrict__ bias,
    const float* __restrict__ res, float* __restrict__ out) {
  int i = blockIdx.x * 256 + threadIdx.x;
  f32x4 s = *(const f32x4*)(parts + (size_t)i * 4);
  s += *(const f32x4*)(parts + 1048576 + (size_t)i * 4);
  s += *(const f32x4*)(parts + 2097152 + (size_t)i * 4);
  s += *(const f32x4*)(parts + 3145728 + (size_t)i * 4);
  s += *(const f32x4*)(res + (size_t)i * 4);
  s += *(const f32x4*)(bias + (i & 63) * 4);
  *(f32x4*)(out + (size_t)i * 4) = s;
}

// ---------------- fused dense-reduce + residual + LN2 ----------------
__global__ __launch_bounds__(256) void reduce_ln(
    const float* __restrict__ parts, const float* __restrict__ bias,
    const float* __restrict__ res, const float* __restrict__ g,
    const float* __restrict__ bta, float* __restrict__ x1o, bf16_t* __restrict__ mo) {
  int row = blockIdx.x * 4 + (threadIdx.x >> 6);
  int l = threadIdx.x & 63;
  size_t base = (size_t)row * 256 + l * 4;
  f32x4 s = *(const f32x4*)(parts + base);
  s += *(const f32x4*)(parts + 1048576 + base);
  s += *(const f32x4*)(parts + 2097152 + base);
  s += *(const f32x4*)(parts + 3145728 + base);
  s += *(const f32x4*)(res + base);
  s += *(const f32x4*)(bias + l * 4);
  *(f32x4*)(x1o + base) = s;
  float sm = s[0] + s[1] + s[2] + s[3];
  float s2 = s[0]*s[0] + s[1]*s[1] + s[2]*s[2] + s[3]*s[3];
#pragma unroll
  for (int o = 1; o < 64; o <<= 1) { sm += __shfl_xor(sm, o, 64); s2 += __shfl_xor(s2, o, 64); }
  float m   = sm * (1.f/256.f);
  float var = s2 * (1.f/256.f) - m * m;
  float rs  = rsqrtf(var + 1e-9f);
  const float4 gv = *(const float4*)(g   + l * 4);
  const float4 bv = *(const float4*)(bta + l * 4);
  bf16x4 yb;
  yb[0] = (bf16_t)((s[0] - m) * rs * gv.x + bv.x);
  yb[1] = (bf16_t)((s[1] - m) * rs * gv.y + bv.y);
  yb[2] = (bf16_t)((s[2] - m) * rs * gv.z + bv.z);
  yb[3] = (bf16_t)((s[3] - m) * rs * gv.w + bv.w);
  *(bf16x4*)(mo + base) = yb;
}

// ---------------- FC1 with gelu ----------------
__global__ __launch_bounds__(256, 2) void gemm_fc1(
    const bf16_t* __restrict__ A, const bf16_t* __restrict__ W,
    const float* __restrict__ bias, bf16_t* __restrict__ out) {
  __shared__ char Asb[2 * 8192];
  __shared__ char Bsb[2 * 8192];
  int row0 = blockIdx.y * 128, col0 = blockIdx.x * 128;
  f32x4 acc[4][4] = {};
  gemm_core(A, W, 256, row0, col0, 0, 8, Asb, Bsb, acc);

  int tid = threadIdx.x, w = tid >> 6, l = tid & 63, l15 = l & 15, lhi = l >> 4;
  int wr = (w >> 1) * 64, wc = (w & 1) * 64;
#pragma unroll
  for (int m = 0; m < 4; ++m)
#pragma unroll
    for (int n = 0; n < 4; ++n)
#pragma unroll
      for (int j = 0; j < 4; ++j) {
        int row = row0 + wr + 16 * m + lhi * 4 + j;
        int col = col0 + wc + 16 * n + l15;
        float t = acc[m][n][j] + bias[col];
        float ge = 0.5f * t * (1.f + tanhf(0.7978845608f * t * (1.f + 0.044715f * t * t)));
        out[(size_t)row * 1024 + col] = (bf16_t)ge;
      }
}

// ---------------- attn_fused2: pass A rowsum + pass B P/PV, both TK=32 ------
// grid 512: bh = bx&15; bx<256: qt=31-(bx>>4) (big first); else qt=(bx-256)>>4.
// 37.6KB LDS; launch_bounds(256,3) -> VGPR cap ~170 (kernel ~125, NO spill),
// 3-4 blocks/CU. This is R15's structure with the register cap fixed.
__global__ __launch_bounds__(256, 3) void attn_fused2(
    const bf16_t* __restrict__ qg, const bf16_t* __restrict__ kg,
    const bf16_t* __restrict__ vt, float* __restrict__ pout,
    bf16_t* __restrict__ ctxo) {
  __shared__ __align__(16) char smem[37632];
  // Ksh dbuf 2x16KB = smem[0..32768)  (shared by pass A and pass B)
  // Psh 4KB @32768; sl 512B @36864; invsh 256B @37376
  char*  Ksh   = smem;
  char*  Psh   = smem + 32768;
  float* sl    = (float*)(smem + 36864);
  float* invsh = (float*)(smem + 37376);

  int bx = blockIdx.x;
  int bh = bx & 15;
  int qt = (bx < 256) ? (31 - (bx >> 4)) : ((bx - 256) >> 4);
  int qbase = qt * 64;

  int tid = threadIdx.x, w = tid >> 6, l = tid & 63;
  int l15 = l & 15, lhi = l >> 4;
  int wm = w >> 1, wn = w & 1;
  const bf16_t* Q  = qg + (size_t)bh * 2048 * 256;
  const bf16_t* K  = kg + (size_t)bh * 2048 * 256;
  const bf16_t* Vt = vt + (size_t)bh * 524288;   // tiled: [kt][256 d][32 s]

  // Q fragments (both passes): rows qbase + wm*32 + m*16 + l15
  bf16x8 qf[2][8];
#pragma unroll
  for (int m = 0; m < 2; ++m)
#pragma unroll
    for (int ks = 0; ks < 8; ++ks)
      qf[m][ks] = *(const bf16x8*)(Q + (size_t)(qbase + wm * 32 + m * 16 + l15) * 256 + ks * 32 + lhi * 8);

  // unified K staging (TK=32): 4 gload16/thread-group into 16KB buffer
#define KSTG(t_) do {                                                           \
    char* kd = Ksh + ((t_) & 1) * 16384 + w * 1024;                             \
    _Pragma("unroll")                                                           \
    for (int j = 0; j < 4; ++j) {                                               \
      int idx = (j * 256 + tid) * 16;                                           \
      int r = idx >> 9; int co = (idx & 511) ^ ((r & 7) << 4);                  \
      gload16(K + (size_t)((t_) * 32 + r) * 256 + (co >> 1), kd + j * 4096);    \
    } } while (0)

  int krow = wn * 16 + l15;          // this lane's K row within tile
  int ksw  = (krow & 7) << 4;
  int nkt = 2 * (qt + 1);            // TK=32 tiles (same count both passes)

  // ================= pass A: masked exp rowsums (TK=32) =================
  KSTG(0);
  if (nkt > 1) KSTG(1);

  float sums[2][4] = {};
  for (int t = 0; t < nkt; ++t) {
    if (t + 1 < nkt) asm volatile("s_waitcnt vmcnt(4)" ::: "memory");
    else             asm volatile("s_waitcnt vmcnt(0)" ::: "memory");
    __builtin_amdgcn_s_barrier();
    const char* Kb = Ksh + (t & 1) * 16384;
    f32x4 acc[2] = {};
    __builtin_amdgcn_s_setprio(1);
#pragma unroll
    for (int ks = 0; ks < 8; ++ks) {
      bf16x8 kb = *(const bf16x8*)(Kb + krow * 512 + ((ks * 64 + lhi * 16) ^ ksw));
      acc[0] = mfma16(qf[0][ks], kb, acc[0]);
      acc[1] = mfma16(qf[1][ks], kb, acc[1]);
    }
    __builtin_amdgcn_s_setprio(0);
#pragma unroll
    for (int m = 0; m < 2; ++m)
#pragma unroll
      for (int j = 0; j < 4; ++j) {
        int qr = qbase + wm * 32 + m * 16 + lhi * 4 + j;
        int kc = t * 32 + krow;
        sums[m][j] += (kc <= qr) ? __expf(acc[m][j] * 0.0625f) : 0.f;
      }
    asm volatile("s_waitcnt lgkmcnt(0)" ::: "memory");
    __builtin_amdgcn_s_barrier();
    if (t + 2 < nkt) KSTG(t + 2);
  }

  // hoisted pass-B prefetch (K tiles 0,1) + first V tile; overlaps reduction.
  KSTG(0);
  if (nkt > 1) KSTG(1);
  bf16x8 vb[4];
#pragma unroll
  for (int n4 = 0; n4 < 4; ++n4) {
    const bf16_t* vp = Vt + ((size_t)0 * 256 + (w * 64 + n4 * 16 + l15)) * 32 + lhi * 8;
    asm volatile("global_load_dwordx4 %0, %1, off" : "=v"(vb[n4]) : "v"(vp) : "memory");
  }

#pragma unroll
  for (int m = 0; m < 2; ++m)
#pragma unroll
    for (int j = 0; j < 4; ++j)
#pragma unroll
      for (int o = 1; o < 16; o <<= 1)
        sums[m][j] += __shfl_xor(sums[m][j], o, 64);
  if (l15 == 0)
#pragma unroll
    for (int m = 0; m < 2; ++m)
#pragma unroll
      for (int j = 0; j < 4; ++j)
        sl[wn * 64 + wm * 32 + m * 16 + lhi * 4 + j] = sums[m][j];
  __syncthreads();
  if (tid < 64) invsh[tid] = 1.f / (sl[tid] + sl[64 + tid]);
  __syncthreads();
  float inv4[2][4];
#pragma unroll
  for (int m = 0; m < 2; ++m)
#pragma unroll
    for (int j = 0; j < 4; ++j)
      inv4[m][j] = invsh[wm * 32 + m * 16 + lhi * 4 + j];
  __syncthreads();

  // ================= pass B: P-write + PV, TK=32 (R14-exact) =============
  f32x4 ctx[4][4] = {};
  for (int t = 0; t < nkt; ++t) {
    if (t == 0)            asm volatile("s_waitcnt vmcnt(8)"  ::: "memory");
    else if (t + 1 == nkt) asm volatile("s_waitcnt vmcnt(6)"  ::: "memory");
    else                   asm volatile("s_waitcnt vmcnt(10)" ::: "memory");
    __builtin_amdgcn_s_barrier();
    const char* Kb = Ksh + (t & 1) * 16384;

    // QK: rows [wm*32,+32) x cols [wn*16,+16)
    f32x4 acc[2] = {};
    __builtin_amdgcn_s_setprio(1);
#pragma unroll
    for (int ks = 0; ks < 8; ++ks) {
      bf16x8 kb = *(const bf16x8*)(Kb + krow * 512 + ((ks * 64 + lhi * 16) ^ ksw));
      acc[0] = mfma16(qf[0][ks], kb, acc[0]);
      acc[1] = mfma16(qf[1][ks], kb, acc[1]);
    }
    __builtin_amdgcn_s_setprio(0);

    // exp/normalize/mask -> Psh (bf16, swz ((rr>>2)&3)<<4)
#pragma unroll
    for (int m = 0; m < 2; ++m)
#pragma unroll
      for (int j = 0; j < 4; ++j) {
        int rr = wm * 32 + m * 16 + lhi * 4 + j;
        int qr = qbase + rr;
        int kc = t * 32 + krow;
        float e = (kc <= qr) ? __expf(acc[m][j] * 0.0625f) * inv4[m][j] : 0.f;
        int addr = rr * 64 + krow * 2;
        *(bf16_t*)(Psh + (addr ^ (((rr >> 2) & 3) << 4))) = (bf16_t)e;
      }
    asm volatile("s_waitcnt lgkmcnt(0)" ::: "memory");   // P writes visible
    __builtin_amdgcn_s_barrier();

    // dump Psh -> pout as f32 (coalesced f32x4); retired by next iter's PV-wait
    {
      int row = tid >> 2;
      int ch  = (tid & 3) * 16;
      bf16x8 p8 = *(const bf16x8*)(Psh + row * 64 + (ch ^ (((row >> 2) & 3) << 4)));
      float* dst = pout + ((size_t)bh * 2048 + qbase + row) * 2048 + t * 32 + (tid & 3) * 8;
      f32x4 lo = { (float)p8[0], (float)p8[1], (float)p8[2], (float)p8[3] };
      f32x4 hi = { (float)p8[4], (float)p8[5], (float)p8[6], (float)p8[7] };
      *(f32x4*)dst = lo;
      *(f32x4*)(dst + 4) = hi;
    }

    // PV: wait for vb(t), then MFMA with P rows from LDS
    if (t + 1 == nkt) asm volatile("s_waitcnt vmcnt(2)" ::: "memory");
    else              asm volatile("s_waitcnt vmcnt(6)" ::: "memory");
    __builtin_amdgcn_sched_barrier(0);
    bf16x8 pa[4];
#pragma unroll
    for (int m4 = 0; m4 < 4; ++m4) {
      int pr = m4 * 16 + l15;
      pa[m4] = *(const bf16x8*)(Psh + ((pr * 64 + lhi * 16) ^ (((pr >> 2) & 3) << 4)));
    }
    __builtin_amdgcn_s_setprio(1);
#pragma unroll
    for (int m4 = 0; m4 < 4; ++m4)
#pragma unroll
      for (int n = 0; n < 4; ++n)
        ctx[m4][n] = mfma16(pa[m4], vb[n], ctx[m4][n]);
    __builtin_amdgcn_s_setprio(0);

    asm volatile("s_waitcnt lgkmcnt(0)" ::: "memory");   // Psh/Ksh reads drained
    __builtin_amdgcn_s_barrier();
    // issue vb(t+1) then KSTG(t+2): queue order [.., v(t+1), P(t+2)]
    if (t + 1 < nkt) {
#pragma unroll
      for (int n4 = 0; n4 < 4; ++n4) {
        const bf16_t* vp = Vt + ((size_t)(t + 1) * 256 + (w * 64 + n4 * 16 + l15)) * 32 + lhi * 8;
        asm volatile("global_load_dwordx4 %0, %1, off" : "=v"(vb[n4]) : "v"(vp) : "memory");
      }
    }
    if (t + 2 < nkt) KSTG(t + 2);
  }
#undef KSTG

  // ctx write: (b, s, h*256 + d) bf16
  int b = bh >> 3, h = bh & 7;
#pragma unroll
  for (int m4 = 0; m4 < 4; ++m4)
#pragma unroll
    for (int n = 0; n < 4; ++n)
#pragma unroll
      for (int j = 0; j < 4; ++j) {
        int qr = qbase + m4 * 16 + lhi * 4 + j;
        ctxo[((size_t)b * 2048 + qr) * 2048 + h * 256 + w * 64 + n * 16 + l15] = (bf16_t)ctx[m4][n][j];
      }

  // zero-fill masked region beyond causal boundary
  int zs = qbase + 64;
  for (int r = 0; r < 64; ++r) {
    size_t base2 = ((size_t)bh * 2048 + qbase + r) * 2048;
    for (int c = zs + tid * 4; c < 2048; c += 1024)
      *(float4*)(pout + base2 + c) = make_float4(0.f, 0.f, 0.f, 0.f);
  }
}

// ---------------- host launch ----------------
extern "C" void kernel_launch(void* const* d_in, const int* in_sizes, int n_in,
                              void* d_out, int out_size, void* d_ws, size_t ws_size,
                              hipStream_t stream) {
  const float* x     = (const float*)d_in[0];
  const float* ln1g  = (const float*)d_in[2];
  const float* ln1b  = (const float*)d_in[3];
  const float* wq_w  = (const float*)d_in[4];
  const float* wq_b  = (const float*)d_in[5];
  const float* wk_w  = (const float*)d_in[6];
  const float* wk_b  = (const float*)d_in[7];
  const float* wv_w  = (const float*)d_in[8];
  const float* wv_b  = (const float*)d_in[9];
  const float* dw    = (const float*)d_in[10];
  const float* db    = (const float*)d_in[11];
  const float* ln2g  = (const float*)d_in[12];
  const float* ln2b  = (const float*)d_in[13];
  const float* f1w   = (const float*)d_in[14];
  const float* f1b   = (const float*)d_in[15];
  const float* f2w   = (const float*)d_in[16];
  const float* f2b   = (const float*)d_in[17];

  char* ws = (char*)d_ws;
  const size_t MB = 1u << 20;
  float*  xn_f = (float*) (ws + 0 * MB);
  bf16_t* xn_b = (bf16_t*)(ws + 4 * MB);
  bf16_t* q_b  = (bf16_t*)(ws + 6 * MB);
  bf16_t* k_b  = (bf16_t*)(ws + 22 * MB);
  bf16_t* ctx_b= (bf16_t*)(ws + 38 * MB);
  bf16_t* vt_b = (bf16_t*)(ws + 54 * MB);
  float*  x1_f = (float*) (ws + 70 * MB);
  bf16_t* m_b  = (bf16_t*)(ws + 74 * MB);
  bf16_t* h_b  = (bf16_t*)(ws + 76 * MB);
  bf16_t* wq_bf = (bf16_t*)(ws + 84 * MB);
  bf16_t* wk_bf = wq_bf + 524288;
  bf16_t* wv_bf = wk_bf + 524288;
  bf16_t* dw_bf = wv_bf + 524288;
  bf16_t* f1_bf = dw_bf + 524288;
  bf16_t* f2_bf = f1_bf + 262144;
  float* parts_d = (float*)q_b;
  float* parts_f = (float*)k_b;

  float* out0 = (float*)d_out;
  float* pout = out0 + 1048576;

  k1_lncvt<<<3584, 256, 0, stream>>>(x, ln1g, ln1b, xn_f, xn_b,
                                     wq_w, wk_w, wv_w, dw, f1w, f2w,
                                     wq_bf, wk_bf, wv_bf, dw_bf, f1_bf, f2_bf);

  gemm_qkv<<<dim3(48, 32), 256, 0, stream>>>(xn_b, wq_bf, wk_bf, wv_bf,
                                             wq_b, wk_b, wv_b, q_b, k_b, vt_b);

  attn_fused2<<<512, 256, 0, stream>>>(q_b, k_b, vt_b, pout, ctx_b);

  gemm_part<<<dim3(2, 32, 4), 256, 0, stream>>>(ctx_b, dw_bf, 2048, 512, parts_d);
  reduce_ln<<<1024, 256, 0, stream>>>(parts_d, db, xn_f, ln2g, ln2b, x1_f, m_b);

  gemm_fc1<<<dim3(8, 32), 256, 0, stream>>>(m_b, f1_bf, f1b, h_b);

  gemm_part<<<dim3(2, 32, 4), 256, 0, stream>>>(h_b, f2_bf, 1024, 256, parts_f);
  reduce4<<<1024, 256, 0, stream>>>(parts_f, f2b, x1_f, out0);
}

// Round 20
// 199.050 us; speedup vs baseline: 2.7052x; 2.7052x over previous
//
#include <hip/hip_runtime.h>
#include <hip/hip_bf16.h>

// TransformerLayer on MI355X (gfx950). Round 20 = exact revert to R17
// (202.7us; tied-best with R14's 200.8). R19's (256,3) allocated 84 VGPR ->
// spills (attn 468us); occupancy axis closed by two independent measurements
// (R15: 64 VGPR @4/CU, R19: 84 @3/CU; kernel needs ~125 -> only 2/CU works).
// This is the validated-best configuration; final state.

typedef __bf16 bf16_t;
typedef __bf16 bf16x8 __attribute__((ext_vector_type(8)));
typedef __bf16 bf16x4 __attribute__((ext_vector_type(4)));
typedef float  f32x4  __attribute__((ext_vector_type(4)));

#define DEV __device__ __forceinline__

DEV f32x4 mfma16(bf16x8 a, bf16x8 b, f32x4 c) {
  return __builtin_amdgcn_mfma_f32_16x16x32_bf16(a, b, c, 0, 0, 0);
}

DEV void gload16(const void* g, void* l) {
  __builtin_amdgcn_global_load_lds(
      (const __attribute__((address_space(1))) unsigned int*)g,
      (__attribute__((address_space(3))) unsigned int*)l, 16, 0, 0);
}

// ---------------- fused LN1 + weight cvt (grid 1024 + 2560) ----------------
__global__ __launch_bounds__(256) void k1_lncvt(
    const float* __restrict__ x, const float* __restrict__ g, const float* __restrict__ bta,
    float* __restrict__ of, bf16_t* __restrict__ ob,
    const float* __restrict__ s0, const float* __restrict__ s1,
    const float* __restrict__ s2, const float* __restrict__ s3,
    const float* __restrict__ s4, const float* __restrict__ s5,
    bf16_t* __restrict__ d0, bf16_t* __restrict__ d1, bf16_t* __restrict__ d2,
    bf16_t* __restrict__ d3, bf16_t* __restrict__ d4, bf16_t* __restrict__ d5) {
  int bid = blockIdx.x;
  if (bid < 1024) {
    int row = bid * 4 + (threadIdx.x >> 6);
    int l = threadIdx.x & 63;
    const float4 v = *(const float4*)(x + (size_t)row * 256 + l * 4);
    float s  = v.x + v.y + v.z + v.w;
    float s2 = v.x*v.x + v.y*v.y + v.z*v.z + v.w*v.w;
#pragma unroll
    for (int o = 1; o < 64; o <<= 1) { s += __shfl_xor(s, o, 64); s2 += __shfl_xor(s2, o, 64); }
    float m   = s * (1.f/256.f);
    float var = s2 * (1.f/256.f) - m * m;
    float rs  = rsqrtf(var + 1e-9f);
    const float4 gv = *(const float4*)(g   + l * 4);
    const float4 bv = *(const float4*)(bta + l * 4);
    float4 y;
    y.x = (v.x - m) * rs * gv.x + bv.x;
    y.y = (v.y - m) * rs * gv.y + bv.y;
    y.z = (v.z - m) * rs * gv.z + bv.z;
    y.w = (v.w - m) * rs * gv.w + bv.w;
    *(float4*)(of + (size_t)row * 256 + l * 4) = y;
    bf16x4 yb = { (bf16_t)y.x, (bf16_t)y.y, (bf16_t)y.z, (bf16_t)y.w };
    *(bf16x4*)(ob + (size_t)row * 256 + l * 4) = yb;
  } else {
    int i = (bid - 1024) * 256 + threadIdx.x;
    const float* s; bf16_t* d; int off;
    if      (i < 131072) { s = s0; d = d0; off = i; }
    else if (i < 262144) { s = s1; d = d1; off = i - 131072; }
    else if (i < 393216) { s = s2; d = d2; off = i - 262144; }
    else if (i < 524288) { s = s3; d = d3; off = i - 393216; }
    else if (i < 589824) { s = s4; d = d4; off = i - 524288; }
    else                 { s = s5; d = d5; off = i - 589824; }
    float4 v = ((const float4*)s)[off];
    bf16x4 o = { (bf16_t)v.x, (bf16_t)v.y, (bf16_t)v.z, (bf16_t)v.w };
    ((bf16x4*)d)[off] = o;
  }
}

// ---------------- 2-phase double-buffered 128x128 GEMM core ----------------
DEV void gemm_core(const bf16_t* __restrict__ A, const bf16_t* __restrict__ W,
                   int lda, int row0, int col0, int k0, int kiters,
                   char* Asb, char* Bsb, f32x4 (&acc)[4][4]) {
  int tid = threadIdx.x, w = tid >> 6, l = tid & 63, l15 = l & 15, lhi = l >> 4;
  int wr = (w >> 1) * 64, wc = (w & 1) * 64;

#define STAGE(buf, kk) do {                                                   \
    char* Ad = Asb + (buf) * 8192 + w * 1024;                                 \
    char* Bd = Bsb + (buf) * 8192 + w * 1024;                                 \
    _Pragma("unroll")                                                         \
    for (int j = 0; j < 2; ++j) {                                             \
      int idx = (j * 256 + tid) * 8; int r = idx >> 5, c = idx & 31;          \
      gload16(A + (size_t)(row0 + r) * lda + (kk) + c, Ad + j * 4096);        \
      gload16(W + (size_t)(col0 + r) * lda + (kk) + c, Bd + j * 4096);        \
    } } while (0)

  STAGE(0, k0);
  for (int t = 0; t < kiters; ++t) {
    int cur = t & 1;
    if (t + 1 < kiters) {
      STAGE(cur ^ 1, k0 + (t + 1) * 32);
      asm volatile("s_waitcnt vmcnt(4)" ::: "memory");
    } else {
      asm volatile("s_waitcnt vmcnt(0)" ::: "memory");
    }
    __builtin_amdgcn_s_barrier();
    asm volatile("" ::: "memory");
    const bf16_t* As = (const bf16_t*)(Asb + cur * 8192);
    const bf16_t* Bs = (const bf16_t*)(Bsb + cur * 8192);
    bf16x8 af[4], bfr[4];
#pragma unroll
    for (int m = 0; m < 4; ++m)
      af[m] = *(const bf16x8*)(As + (wr + 16 * m + l15) * 32 + lhi * 8);
#pragma unroll
    for (int n = 0; n < 4; ++n)
      bfr[n] = *(const bf16x8*)(Bs + (wc + 16 * n + l15) * 32 + lhi * 8);
#pragma unroll
    for (int m = 0; m < 4; ++m)
#pragma unroll
      for (int n = 0; n < 4; ++n)
        acc[m][n] = mfma16(af[m], bfr[n], acc[m][n]);
    asm volatile("s_waitcnt lgkmcnt(0)" ::: "memory");
    __builtin_amdgcn_s_barrier();
  }
#undef STAGE
}

// ---------------- fused QKV: grid (48, 32); V written TILED ----------------
// vt layout: [bh][kt=s/32][256 d][32 s] bf16 (16KB per tile)
__global__ __launch_bounds__(256, 2) void gemm_qkv(
    const bf16_t* __restrict__ A,
    const bf16_t* __restrict__ W0, const bf16_t* __restrict__ W1, const bf16_t* __restrict__ W2,
    const float* __restrict__ b0, const float* __restrict__ b1, const float* __restrict__ b2,
    bf16_t* __restrict__ qo, bf16_t* __restrict__ ko, bf16_t* __restrict__ vto) {
  __shared__ char smem[34816];   // staging 32KB | V-transpose 128x136 bf16
  char* Asb = smem;
  char* Bsb = smem + 16384;
  int bx = blockIdx.x;
  int wsel = bx >> 4, cb = bx & 15;
  const bf16_t* W    = wsel == 0 ? W0 : (wsel == 1 ? W1 : W2);
  const float*  bias = wsel == 0 ? b0 : (wsel == 1 ? b1 : b2);
  int row0 = blockIdx.y * 128, col0 = cb * 128;
  f32x4 acc[4][4] = {};
  gemm_core(A, W, 256, row0, col0, 0, 8, Asb, Bsb, acc);

  int tid = threadIdx.x, w = tid >> 6, l = tid & 63, l15 = l & 15, lhi = l >> 4;
  int wr = (w >> 1) * 64, wc = (w & 1) * 64;

  if (wsel < 2) {
    bf16_t* out = wsel == 0 ? qo : ko;
#pragma unroll
    for (int m = 0; m < 4; ++m)
#pragma unroll
      for (int n = 0; n < 4; ++n)
#pragma unroll
        for (int j = 0; j < 4; ++j) {
          int row = row0 + wr + 16 * m + lhi * 4 + j;
          int col = col0 + wc + 16 * n + l15;
          float v = acc[m][n][j] + bias[col];
          out[((size_t)((row >> 11) * 8 + (col >> 8)) * 2048 + (row & 2047)) * 256 + (col & 255)] = (bf16_t)v;
        }
  } else {
    // V: transpose in LDS, write TILED V^T: vt[bh][kt][d][32]
    __syncthreads();   // full drain before overwriting staging LDS
    bf16_t* T = (bf16_t*)smem;   // [128 d][136 stride] bf16
#pragma unroll
    for (int m = 0; m < 4; ++m)
#pragma unroll
      for (int n = 0; n < 4; ++n) {
        int d = wc + 16 * n + l15;
        int s = wr + 16 * m + lhi * 4;
        bf16x4 v4;
#pragma unroll
        for (int j = 0; j < 4; ++j) v4[j] = (bf16_t)(acc[m][n][j] + bias[col0 + d]);
        *(bf16x4*)(T + d * 136 + s) = v4;
      }
    __syncthreads();
    int bh = ((row0 >> 11) << 3) + (col0 >> 8);
    int d0 = col0 & 255, s0g = row0 & 2047;
#pragma unroll
    for (int p = 0; p < 8; ++p) {
      int idx = p * 256 + tid;
      int d = idx >> 4, c = (idx & 15) * 8;
      bf16x8 v8 = *(const bf16x8*)(T + d * 136 + c);
      int kt = (s0g + c) >> 5, so = c & 31;
      *(bf16x8*)(vto + (((size_t)bh * 64 + kt) * 256 + d0 + d) * 32 + so) = v8;
    }
  }
}

// ---------------- split-K partial GEMM: N=256, grid (2, 32, 4) ----------------
__global__ __launch_bounds__(256, 2) void gemm_part(
    const bf16_t* __restrict__ A, const bf16_t* __restrict__ W,
    int lda, int ksub, float* __restrict__ parts) {
  __shared__ char Asb[2 * 8192];
  __shared__ char Bsb[2 * 8192];
  int z = blockIdx.z;
  int row0 = blockIdx.y * 128, col0 = blockIdx.x * 128;
  f32x4 acc[4][4] = {};
  gemm_core(A, W, lda, row0, col0, z * ksub, ksub >> 5, Asb, Bsb, acc);

  int tid = threadIdx.x, w = tid >> 6, l = tid & 63, l15 = l & 15, lhi = l >> 4;
  int wr = (w >> 1) * 64, wc = (w & 1) * 64;
  float* p = parts + (size_t)z * 1048576;
#pragma unroll
  for (int m = 0; m < 4; ++m)
#pragma unroll
    for (int n = 0; n < 4; ++n)
#pragma unroll
      for (int j = 0; j < 4; ++j) {
        int row = row0 + wr + 16 * m + lhi * 4 + j;
        int col = col0 + wc + 16 * n + l15;
        p[(size_t)row * 256 + col] = acc[m][n][j];
      }
}

// ---------------- reduce 4 partials + bias + residual (final out) ----------------
__global__ __launch_bounds__(256) void reduce4(
    const float* __restrict__ parts, const float* __restrict__ bias,
    const float* __restrict__ res, float* __restrict__ out) {
  int i = blockIdx.x * 256 + threadIdx.x;
  f32x4 s = *(const f32x4*)(parts + (size_t)i * 4);
  s += *(const f32x4*)(parts + 1048576 + (size_t)i * 4);
  s += *(const f32x4*)(parts + 2097152 + (size_t)i * 4);
  s += *(const f32x4*)(parts + 3145728 + (size_t)i * 4);
  s += *(const f32x4*)(res + (size_t)i * 4);
  s += *(const f32x4*)(bias + (i & 63) * 4);
  *(f32x4*)(out + (size_t)i * 4) = s;
}

// ---------------- fused dense-reduce + residual + LN2 ----------------
__global__ __launch_bounds__(256) void reduce_ln(
    const float* __restrict__ parts, const float* __restrict__ bias,
    const float* __restrict__ res, const float* __restrict__ g,
    const float* __restrict__ bta, float* __restrict__ x1o, bf16_t* __restrict__ mo) {
  int row = blockIdx.x * 4 + (threadIdx.x >> 6);
  int l = threadIdx.x & 63;
  size_t base = (size_t)row * 256 + l * 4;
  f32x4 s = *(const f32x4*)(parts + base);
  s += *(const f32x4*)(parts + 1048576 + base);
  s += *(const f32x4*)(parts + 2097152 + base);
  s += *(const f32x4*)(parts + 3145728 + base);
  s += *(const f32x4*)(res + base);
  s += *(const f32x4*)(bias + l * 4);
  *(f32x4*)(x1o + base) = s;
  float sm = s[0] + s[1] + s[2] + s[3];
  float s2 = s[0]*s[0] + s[1]*s[1] + s[2]*s[2] + s[3]*s[3];
#pragma unroll
  for (int o = 1; o < 64; o <<= 1) { sm += __shfl_xor(sm, o, 64); s2 += __shfl_xor(s2, o, 64); }
  float m   = sm * (1.f/256.f);
  float var = s2 * (1.f/256.f) - m * m;
  float rs  = rsqrtf(var + 1e-9f);
  const float4 gv = *(const float4*)(g   + l * 4);
  const float4 bv = *(const float4*)(bta + l * 4);
  bf16x4 yb;
  yb[0] = (bf16_t)((s[0] - m) * rs * gv.x + bv.x);
  yb[1] = (bf16_t)((s[1] - m) * rs * gv.y + bv.y);
  yb[2] = (bf16_t)((s[2] - m) * rs * gv.z + bv.z);
  yb[3] = (bf16_t)((s[3] - m) * rs * gv.w + bv.w);
  *(bf16x4*)(mo + base) = yb;
}

// ---------------- FC1 with gelu ----------------
__global__ __launch_bounds__(256, 2) void gemm_fc1(
    const bf16_t* __restrict__ A, const bf16_t* __restrict__ W,
    const float* __restrict__ bias, bf16_t* __restrict__ out) {
  __shared__ char Asb[2 * 8192];
  __shared__ char Bsb[2 * 8192];
  int row0 = blockIdx.y * 128, col0 = blockIdx.x * 128;
  f32x4 acc[4][4] = {};
  gemm_core(A, W, 256, row0, col0, 0, 8, Asb, Bsb, acc);

  int tid = threadIdx.x, w = tid >> 6, l = tid & 63, l15 = l & 15, lhi = l >> 4;
  int wr = (w >> 1) * 64, wc = (w & 1) * 64;
#pragma unroll
  for (int m = 0; m < 4; ++m)
#pragma unroll
    for (int n = 0; n < 4; ++n)
#pragma unroll
      for (int j = 0; j < 4; ++j) {
        int row = row0 + wr + 16 * m + lhi * 4 + j;
        int col = col0 + wc + 16 * n + l15;
        float t = acc[m][n][j] + bias[col];
        float ge = 0.5f * t * (1.f + tanhf(0.7978845608f * t * (1.f + 0.044715f * t * t)));
        out[(size_t)row * 1024 + col] = (bf16_t)ge;
      }
}

// ---------------- attn_fused2: pass A rowsum (TK=64) + pass B P/PV (TK=32) --
// grid 512: bh = bx&15; bx<256: qt=31-(bx>>4) (big first); else qt=(bx-256)>>4.
__global__ __launch_bounds__(256, 2) void attn_fused2(
    const bf16_t* __restrict__ qg, const bf16_t* __restrict__ kg,
    const bf16_t* __restrict__ vt, float* __restrict__ pout,
    bf16_t* __restrict__ ctxo) {
  __shared__ __align__(16) char smem[66304];
  // pass A: KA dbuf 2x32KB = smem[0..65536)
  // pass B: KB2 dbuf 2x16KB = smem[0..32768), Psh 4KB @32768
  // sl 512B @65536, invsh 256B @66048
  char*  KA    = smem;
  char*  KB2   = smem;
  char*  Psh   = smem + 32768;
  float* sl    = (float*)(smem + 65536);
  float* invsh = (float*)(smem + 66048);

  int bx = blockIdx.x;
  int bh = bx & 15;
  int qt = (bx < 256) ? (31 - (bx >> 4)) : ((bx - 256) >> 4);
  int qbase = qt * 64;

  int tid = threadIdx.x, w = tid >> 6, l = tid & 63;
  int l15 = l & 15, lhi = l >> 4;
  int wm = w >> 1, wn = w & 1;
  const bf16_t* Q  = qg + (size_t)bh * 2048 * 256;
  const bf16_t* K  = kg + (size_t)bh * 2048 * 256;
  const bf16_t* Vt = vt + (size_t)bh * 524288;   // tiled: [kt][256 d][32 s]

  // Q fragments (both passes): rows qbase + wm*32 + m*16 + l15
  bf16x8 qf[2][8];
#pragma unroll
  for (int m = 0; m < 2; ++m)
#pragma unroll
    for (int ks = 0; ks < 8; ++ks)
      qf[m][ks] = *(const bf16x8*)(Q + (size_t)(qbase + wm * 32 + m * 16 + l15) * 256 + ks * 32 + lhi * 8);

  // ================= pass A: masked exp rowsums =================
  int nktA = qt + 1;
#define RSTAGE(t_) do {                                                        \
    char* dst = KA + ((t_) & 1) * 32768 + w * 1024;                            \
    _Pragma("unroll")                                                          \
    for (int j = 0; j < 8; ++j) {                                              \
      int idx = (j * 256 + tid) * 16; int r = idx >> 9;                        \
      int co = (idx & 511) ^ ((r & 7) << 4);                                   \
      gload16(K + (size_t)((t_) * 64 + r) * 256 + (co >> 1), dst + j * 4096);  \
    } } while (0)

  RSTAGE(0);
  if (nktA > 1) RSTAGE(1);

  float sums[2][4] = {};
  for (int t = 0; t < nktA; ++t) {
    if (t + 1 < nktA) asm volatile("s_waitcnt vmcnt(8)" ::: "memory");
    else              asm volatile("s_waitcnt vmcnt(0)" ::: "memory");
    __builtin_amdgcn_s_barrier();
    const char* Kb = KA + (t & 1) * 32768;
    f32x4 acc[2][2] = {};
    __builtin_amdgcn_s_setprio(1);
#pragma unroll
    for (int ks = 0; ks < 8; ++ks) {
#pragma unroll
      for (int n2 = 0; n2 < 2; ++n2) {
        int row = wn * 32 + n2 * 16 + l15;
        bf16x8 kb = *(const bf16x8*)(Kb + row * 512 + ((ks * 64 + lhi * 16) ^ ((row & 7) << 4)));
#pragma unroll
        for (int m = 0; m < 2; ++m)
          acc[m][n2] = mfma16(qf[m][ks], kb, acc[m][n2]);
      }
    }
    __builtin_amdgcn_s_setprio(0);
#pragma unroll
    for (int m = 0; m < 2; ++m)
#pragma unroll
      for (int n2 = 0; n2 < 2; ++n2)
#pragma unroll
        for (int j = 0; j < 4; ++j) {
          int qr = qbase + wm * 32 + m * 16 + lhi * 4 + j;
          int kc = t * 64 + wn * 32 + n2 * 16 + l15;
          sums[m][j] += (kc <= qr) ? __expf(acc[m][n2][j] * 0.0625f) : 0.f;
        }
    asm volatile("s_waitcnt lgkmcnt(0)" ::: "memory");
    __builtin_amdgcn_s_barrier();
    if (t + 2 < nktA) RSTAGE(t + 2);
  }
#undef RSTAGE

  // ---- pass B staging macro (K only, 4 loads) ----
#define PSTAGE(t_) do {                                                         \
    char* kd = KB2 + ((t_) & 1) * 16384 + w * 1024;                             \
    _Pragma("unroll")                                                           \
    for (int j = 0; j < 4; ++j) {                                               \
      int idx = (j * 256 + tid) * 16;                                           \
      int r = idx >> 9; int co = (idx & 511) ^ ((r & 7) << 4);                  \
      gload16(K + (size_t)((t_) * 32 + r) * 256 + (co >> 1), kd + j * 4096);    \
    } } while (0)

  // hoisted pass-B prefetch (K tiles 0,1) + first V tile; the reduction's
  // __syncthreads() drains vmcnt, so these complete under the reduction.
  PSTAGE(0);
  PSTAGE(1);
  bf16x8 vb[4];
#pragma unroll
  for (int n4 = 0; n4 < 4; ++n4) {
    const bf16_t* vp = Vt + ((size_t)0 * 256 + (w * 64 + n4 * 16 + l15)) * 32 + lhi * 8;
    asm volatile("global_load_dwordx4 %0, %1, off" : "=v"(vb[n4]) : "v"(vp) : "memory");
  }

#pragma unroll
  for (int m = 0; m < 2; ++m)
#pragma unroll
    for (int j = 0; j < 4; ++j)
#pragma unroll
      for (int o = 1; o < 16; o <<= 1)
        sums[m][j] += __shfl_xor(sums[m][j], o, 64);
  if (l15 == 0)
#pragma unroll
    for (int m = 0; m < 2; ++m)
#pragma unroll
      for (int j = 0; j < 4; ++j)
        sl[wn * 64 + wm * 32 + m * 16 + lhi * 4 + j] = sums[m][j];
  __syncthreads();
  if (tid < 64) invsh[tid] = 1.f / (sl[tid] + sl[64 + tid]);
  __syncthreads();
  float inv4[2][4];
#pragma unroll
  for (int m = 0; m < 2; ++m)
#pragma unroll
    for (int j = 0; j < 4; ++j)
      inv4[m][j] = invsh[wm * 32 + m * 16 + lhi * 4 + j];
  __syncthreads();   // all invsh reads done; drains vmcnt (prologue complete)

  // ================= pass B: P-write + PV, TK=32 =============
  int nktB = 2 * (qt + 1);
  int krow = wn * 16 + l15;
  f32x4 ctx[4][4] = {};
  for (int t = 0; t < nktB; ++t) {
    if (t == 0)             asm volatile("s_waitcnt vmcnt(8)"  ::: "memory");
    else if (t + 1 == nktB) asm volatile("s_waitcnt vmcnt(6)"  ::: "memory");
    else                    asm volatile("s_waitcnt vmcnt(10)" ::: "memory");
    __builtin_amdgcn_s_barrier();
    const char* Kb = KB2 + (t & 1) * 16384;

    // QK: rows [wm*32,+32) x cols [wn*16,+16)
    f32x4 acc[2] = {};
    __builtin_amdgcn_s_setprio(1);
#pragma unroll
    for (int ks = 0; ks < 8; ++ks) {
      bf16x8 kb = *(const bf16x8*)(Kb + krow * 512 + ((ks * 64 + lhi * 16) ^ ((krow & 7) << 4)));
      acc[0] = mfma16(qf[0][ks], kb, acc[0]);
      acc[1] = mfma16(qf[1][ks], kb, acc[1]);
    }
    __builtin_amdgcn_s_setprio(0);

    // exp/normalize/mask -> Psh (bf16, swz ((rr>>2)&3)<<4)
#pragma unroll
    for (int m = 0; m < 2; ++m)
#pragma unroll
      for (int j = 0; j < 4; ++j) {
        int rr = wm * 32 + m * 16 + lhi * 4 + j;
        int qr = qbase + rr;
        int kc = t * 32 + krow;
        float e = (kc <= qr) ? __expf(acc[m][j] * 0.0625f) * inv4[m][j] : 0.f;
        int addr = rr * 64 + krow * 2;
        *(bf16_t*)(Psh + (addr ^ (((rr >> 2) & 3) << 4))) = (bf16_t)e;
      }
    asm volatile("s_waitcnt lgkmcnt(0)" ::: "memory");   // P writes visible
    __builtin_amdgcn_s_barrier();

    // dump Psh -> pout as f32 (coalesced f32x4); retired by next iter's PV-wait
    {
      int row = tid >> 2;
      int ch  = (tid & 3) * 16;
      bf16x8 p8 = *(const bf16x8*)(Psh + row * 64 + (ch ^ (((row >> 2) & 3) << 4)));
      float* dst = pout + ((size_t)bh * 2048 + qbase + row) * 2048 + t * 32 + (tid & 3) * 8;
      f32x4 lo = { (float)p8[0], (float)p8[1], (float)p8[2], (float)p8[3] };
      f32x4 hi = { (float)p8[4], (float)p8[5], (float)p8[6], (float)p8[7] };
      *(f32x4*)dst = lo;
      *(f32x4*)(dst + 4) = hi;
    }

    // PV: wait for vb(t), then MFMA with P rows from LDS
    if (t + 1 == nktB) asm volatile("s_waitcnt vmcnt(2)" ::: "memory");
    else               asm volatile("s_waitcnt vmcnt(6)" ::: "memory");
    __builtin_amdgcn_sched_barrier(0);
    bf16x8 pa[4];
#pragma unroll
    for (int m4 = 0; m4 < 4; ++m4) {
      int pr = m4 * 16 + l15;
      pa[m4] = *(const bf16x8*)(Psh + ((pr * 64 + lhi * 16) ^ (((pr >> 2) & 3) << 4)));
    }
    __builtin_amdgcn_s_setprio(1);
#pragma unroll
    for (int m4 = 0; m4 < 4; ++m4)
#pragma unroll
      for (int n = 0; n < 4; ++n)
        ctx[m4][n] = mfma16(pa[m4], vb[n], ctx[m4][n]);
    __builtin_amdgcn_s_setprio(0);

    asm volatile("s_waitcnt lgkmcnt(0)" ::: "memory");   // Psh/Ksh reads drained
    __builtin_amdgcn_s_barrier();
    // issue vb(t+1) then PSTAGE(t+2): keeps queue order [.., v(t+1), P(t+2)]
    if (t + 1 < nktB) {
#pragma unroll
      for (int n4 = 0; n4 < 4; ++n4) {
        const bf16_t* vp = Vt + ((size_t)(t + 1) * 256 + (w * 64 + n4 * 16 + l15)) * 32 + lhi * 8;
        asm volatile("global_load_dwordx4 %0, %1, off" : "=v"(vb[n4]) : "v"(vp) : "memory");
      }
    }
    if (t + 2 < nktB) PSTAGE(t + 2);
  }
#undef PSTAGE

  // ctx write: (b, s, h*256 + d) bf16
  int b = bh >> 3, h = bh & 7;
#pragma unroll
  for (int m4 = 0; m4 < 4; ++m4)
#pragma unroll
    for (int n = 0; n < 4; ++n)
#pragma unroll
      for (int j = 0; j < 4; ++j) {
        int qr = qbase + m4 * 16 + lhi * 4 + j;
        ctxo[((size_t)b * 2048 + qr) * 2048 + h * 256 + w * 64 + n * 16 + l15] = (bf16_t)ctx[m4][n][j];
      }

  // zero-fill masked region beyond causal boundary
  int zs = qbase + 64;
  for (int r = 0; r < 64; ++r) {
    size_t base2 = ((size_t)bh * 2048 + qbase + r) * 2048;
    for (int c = zs + tid * 4; c < 2048; c += 1024)
      *(float4*)(pout + base2 + c) = make_float4(0.f, 0.f, 0.f, 0.f);
  }
}

// ---------------- host launch ----------------
extern "C" void kernel_launch(void* const* d_in, const int* in_sizes, int n_in,
                              void* d_out, int out_size, void* d_ws, size_t ws_size,
                              hipStream_t stream) {
  const float* x     = (const float*)d_in[0];
  const float* ln1g  = (const float*)d_in[2];
  const float* ln1b  = (const float*)d_in[3];
  const float* wq_w  = (const float*)d_in[4];
  const float* wq_b  = (const float*)d_in[5];
  const float* wk_w  = (const float*)d_in[6];
  const float* wk_b  = (const float*)d_in[7];
  const float* wv_w  = (const float*)d_in[8];
  const float* wv_b  = (const float*)d_in[9];
  const float* dw    = (const float*)d_in[10];
  const float* db    = (const float*)d_in[11];
  const float* ln2g  = (const float*)d_in[12];
  const float* ln2b  = (const float*)d_in[13];
  const float* f1w   = (const float*)d_in[14];
  const float* f1b   = (const float*)d_in[15];
  const float* f2w   = (const float*)d_in[16];
  const float* f2b   = (const float*)d_in[17];

  char* ws = (char*)d_ws;
  const size_t MB = 1u << 20;
  float*  xn_f = (float*) (ws + 0 * MB);
  bf16_t* xn_b = (bf16_t*)(ws + 4 * MB);
  bf16_t* q_b  = (bf16_t*)(ws + 6 * MB);
  bf16_t* k_b  = (bf16_t*)(ws + 22 * MB);
  bf16_t* ctx_b= (bf16_t*)(ws + 38 * MB);
  bf16_t* vt_b = (bf16_t*)(ws + 54 * MB);
  float*  x1_f = (float*) (ws + 70 * MB);
  bf16_t* m_b  = (bf16_t*)(ws + 74 * MB);
  bf16_t* h_b  = (bf16_t*)(ws + 76 * MB);
  bf16_t* wq_bf = (bf16_t*)(ws + 84 * MB);
  bf16_t* wk_bf = wq_bf + 524288;
  bf16_t* wv_bf = wk_bf + 524288;
  bf16_t* dw_bf = wv_bf + 524288;
  bf16_t* f1_bf = dw_bf + 524288;
  bf16_t* f2_bf = f1_bf + 262144;
  float* parts_d = (float*)q_b;
  float* parts_f = (float*)k_b;

  float* out0 = (float*)d_out;
  float* pout = out0 + 1048576;

  k1_lncvt<<<3584, 256, 0, stream>>>(x, ln1g, ln1b, xn_f, xn_b,
                                     wq_w, wk_w, wv_w, dw, f1w, f2w,
                                     wq_bf, wk_bf, wv_bf, dw_bf, f1_bf, f2_bf);

  gemm_qkv<<<dim3(48, 32), 256, 0, stream>>>(xn_b, wq_bf, wk_bf, wv_bf,
                                             wq_b, wk_b, wv_b, q_b, k_b, vt_b);

  attn_fused2<<<512, 256, 0, stream>>>(q_b, k_b, vt_b, pout, ctx_b);

  gemm_part<<<dim3(2, 32, 4), 256, 0, stream>>>(ctx_b, dw_bf, 2048, 512, parts_d);
  reduce_ln<<<1024, 256, 0, stream>>>(parts_d, db, xn_f, ln2g, ln2b, x1_f, m_b);

  gemm_fc1<<<dim3(8, 32), 256, 0, stream>>>(m_b, f1_bf, f1b, h_b);

  gemm_part<<<dim3(2, 32, 4), 256, 0, stream>>>(h_b, f2_bf, 1024, 256, parts_f);
  reduce4<<<1024, 256, 0, stream>>>(parts_f, f2b, x1_f, out0);
}